// Round 10
// baseline (102.467 us; speedup 1.0000x reference)
//
#include <hip/hip_runtime.h>
#include <cstdint>

#define BB 16
#define NN 65536
#define DD 32
#define KK 64
#define DELTA_V 0.5f
#define DELTA_D 1.5f
#define GRID 512          // 32 blocks/batch; 512 thr; 2 blocks/CU (LDS-capped)
#define PPB 2048          // points per block
#define WPTS 256          // points per wave (8 waves)
#define NSTG 4            // 64-point stages per wave

typedef short bf16x8 __attribute__((ext_vector_type(8)));
typedef float f32x16 __attribute__((ext_vector_type(16)));

__device__ __forceinline__ short f2bf(float x) {
    union { float f; unsigned u; } v; v.f = x;
    const unsigned r = v.u + 0x7FFFu + ((v.u >> 16) & 1u);  // RNE
    return (short)(r >> 16);
}

// --- coherent flag ops: RELAXED RMW polls, RELEASE arrive, ACQUIRE on exit
__device__ __forceinline__ int fpoll(int* p) {
    return __hip_atomic_fetch_add(p, 0, __ATOMIC_RELAXED, __HIP_MEMORY_SCOPE_AGENT);
}
__device__ __forceinline__ void arrive(int* p) {
    __hip_atomic_fetch_add(p, 1, __ATOMIC_RELEASE, __HIP_MEMORY_SCOPE_AGENT);
}
__device__ __forceinline__ void spinge(int* p, int tgt) {
    const long long t0 = clock64();
    while (fpoll(p) < tgt) {
        __builtin_amdgcn_s_sleep(8);
        if (clock64() - t0 > (long long)2e8) break;   // fail loud, not hung
    }
    (void)__hip_atomic_load(p, __ATOMIC_ACQUIRE, __HIP_MEMORY_SCOPE_AGENT);
}

__global__ __launch_bounds__(64) void k_init(int* bar) {
    for (int j = threadIdx.x; j < 2048; j += 64) bar[j] = 0;
}

// flags: barrierA[b]=bar[b*32]; barrierB[b]=bar[b*32+8]; auxdone=bar[512];
//        ticket=bar[544]

__global__ __launch_bounds__(512, 4) void k_fused(
    const float* __restrict__ emb, const int* __restrict__ ids,
    const int* __restrict__ mask, float* parts, float* pcnt, float* mu,
    float* varpart, float* aux, int* bar, float* __restrict__ out)
{
    __shared__ float tb[8][64][36];   // 73.7 KB multi-purpose
    __shared__ float lc2[8][64];      // 2 KB (also slice-reduce scratch)
    __shared__ float red[8];
    __shared__ float sf[4][BB];
    __shared__ float scq[2];          // rcp counts for this block's 2 k-rows
    __shared__ int s_last;
    const int tid  = threadIdx.x;
    const int w    = tid >> 6, lane = tid & 63;
    const int half = lane >> 5, d32 = lane & 31;
    const int pl   = lane >> 3, pc = lane & 7;
    const int gblk = blockIdx.x;
    const int b    = gblk >> 5;
    const size_t pw = (size_t)b * NN + (size_t)(gblk & 31) * PPB + (size_t)w * WPTS;

    // ======== phase 1: one-hot MFMA partial segment-sums ========
    {
        f32x16 acc0 = {}, acc1 = {};
        int c0 = 0, c1 = 0;
        const int m0 = d32, m1 = d32 + 32;
        float (*T)[36] = tb[w];
        const float4* epb  = (const float4*)(emb + pw * DD);
        const int*    idsb = ids + pw;
        const int*    mskb = mask + pw;

        float4 r[8]; int idr, mkr;
#pragma unroll
        for (int i = 0; i < 8; ++i) r[i] = epb[i * 64 + lane];
        idr = idsb[lane]; mkr = mskb[lane];

#pragma unroll
        for (int s = 0; s < NSTG; ++s) {
            float4 r2[8]; int idr2 = 0, mkr2 = 0;
            if (s < NSTG - 1) {                  // prefetch next stage
                const float4* ep4 = epb + (s + 1) * 512;
#pragma unroll
                for (int i = 0; i < 8; ++i) r2[i] = ep4[i * 64 + lane];
                idr2 = idsb[(s + 1) * 64 + lane];
                mkr2 = mskb[(s + 1) * 64 + lane];
            }
            const int vid = (mkr != 0 && (unsigned)idr < KK) ? idr : -1;
#pragma unroll
            for (int i = 0; i < 8; ++i)
                *(float4*)&T[i * 8 + pl][4 * pc] = r[i];
#pragma unroll
            for (int q = 0; q < 4; ++q) {
                bf16x8 bfB, a0, a1;
#pragma unroll
                for (int e = 0; e < 8; ++e) {
                    bfB[e] = f2bf(T[q * 16 + 8 * half + e][d32]);
                    const int s_lo = __builtin_amdgcn_readlane(vid, q * 16 + e);
                    const int s_hi = __builtin_amdgcn_readlane(vid, q * 16 + 8 + e);
                    const int sel  = half ? s_hi : s_lo;
                    const bool h0 = (sel == m0), h1 = (sel == m1);
                    a0[e] = h0 ? (short)0x3F80 : (short)0;   // bf16 1.0
                    a1[e] = h1 ? (short)0x3F80 : (short)0;
                    c0 += h0 ? 1 : 0;
                    c1 += h1 ? 1 : 0;
                }
                acc0 = __builtin_amdgcn_mfma_f32_32x32x16_bf16(a0, bfB, acc0, 0, 0, 0);
                acc1 = __builtin_amdgcn_mfma_f32_32x32x16_bf16(a1, bfB, acc1, 0, 0, 0);
            }
            if (s < NSTG - 1) {
#pragma unroll
                for (int i = 0; i < 8; ++i) r[i] = r2[i];
                idr = idr2; mkr = mkr2;
            }
        }
#pragma unroll
        for (int rr = 0; rr < 16; ++rr) {
            const int mrow = (rr & 3) + 8 * (rr >> 2) + 4 * half;
            T[mrow][d32]      = acc0[rr];
            T[32 + mrow][d32] = acc1[rr];
        }
        c0 += __shfl_down(c0, 32);
        c1 += __shfl_down(c1, 32);
        if (lane < 32) { lc2[w][lane] = (float)c0; lc2[w][lane + 32] = (float)c1; }
        __syncthreads();

        float* pb = parts + (size_t)gblk * 2048;
        for (int i = tid; i < 2048; i += 512) {
            const int row = i >> 5, col = i & 31;
            float s = 0.f;
#pragma unroll
            for (int ww = 0; ww < 8; ++ww) s += tb[ww][row][col];
            pb[i] = s;
        }
        if (tid < KK) {
            float s = 0.f;
#pragma unroll
            for (int ww = 0; ww < 8; ++ww) s += lc2[ww][tid];
            pcnt[(size_t)gblk * KK + tid] = s;
        }
    }
    __syncthreads();                  // all waves' stores drained (vmcnt)

    // ======== per-batch barrier A ========
    if (tid == 0) { arrive(&bar[b * 32]); spinge(&bar[b * 32], 32); }
    __syncthreads();

    // ======== hierarchical slice reduce: this block owns 2 k-rows ========
    {
        const int kb = (gblk & 31) * 2;
        if (tid < 64) {               // counts for k = kb + (tid>>5)
            const int k = kb + (tid >> 5);
            const int j = tid & 31;
            float cv = pcnt[((size_t)(b * 32 + j)) * KK + k];
            for (int off = 16; off; off >>= 1) cv += __shfl_down(cv, off);
            if ((tid & 31) == 0) {
                mu[((size_t)b * KK + k) * 36 + 32] = cv;
                const float rc = 1.f / fmaxf(cv, 1.f);
                mu[((size_t)b * KK + k) * 36 + 33] = rc;
                scq[tid >> 5] = rc;
            }
        }
        __syncthreads();
        const int e  = tid & 63;      // element within the 2 k-rows
        const int jg = tid >> 6;      // 0..7
        float s = 0.f;
#pragma unroll
        for (int jj = 0; jj < 4; ++jj)
            s += parts[((size_t)(b * 32 + jg * 4 + jj)) * 2048 + kb * 32 + e];
        lc2[jg][e] = s;
        __syncthreads();
        if (tid < 64) {
            float t = 0.f;
#pragma unroll
            for (int g = 0; g < 8; ++g) t += lc2[g][tid];
            mu[((size_t)b * KK + kb + (tid >> 5)) * 36 + (tid & 31)] =
                t * scq[tid >> 5];
        }
    }
    __syncthreads();

    // ======== per-batch barrier B ========
    if (tid == 0) { arrive(&bar[b * 32 + 8]); spinge(&bar[b * 32 + 8], 32); }
    __syncthreads();

    // ======== load mu[b] into LDS ========
    float (*smu)[36] = tb[0];
    {
        const float* mub = mu + (size_t)b * KK * 36;
        for (int i = tid; i < KK * 36; i += 512) ((float*)smu)[i] = mub[i];
    }
    __syncthreads();

    // ======== designated block per batch: reg + push losses ========
    if ((gblk & 31) == 0) {
        float ninst = 0.f;
        if (tid < KK) {
            const float c = smu[tid][32];
            const float pres = (c > 0.f) ? 1.f : 0.f;
            float sq = 0.f;
#pragma unroll
            for (int d = 0; d < DD; ++d) { const float m = smu[tid][d]; sq = fmaf(m, m, sq); }
            float nm = ((sq > 0.f) ? sqrtf(sq) : 0.f) * pres;
            float pn = pres;
            for (int off = 32; off; off >>= 1) {
                pn += __shfl_down(pn, off);
                nm += __shfl_down(nm, off);
            }
            if (tid == 0) {
                ninst = pn;
                aux[b]      = nm / fmaxf(pn, 1.f);   // reg_b
                aux[32 + b] = pn;                    // num_inst
            }
        }
        float acc = 0.f;
        for (int idx = tid; idx < KK * KK; idx += 512) {
            const int i = idx >> 6, j = idx & 63;
            if (i < j && smu[i][32] > 0.f && smu[j][32] > 0.f) {
                float dsq = 0.f;
#pragma unroll
                for (int d = 0; d < DD; ++d) {
                    const float df = smu[i][d] - smu[j][d];
                    dsq = fmaf(df, df, dsq);
                }
                const float pd = (dsq > 0.f) ? sqrtf(dsq) : 0.f;
                const float pen = fmaxf(2.f * DELTA_D - pd, 0.f);
                acc = fmaf(pen, pen, acc);
            }
        }
        for (int off = 32; off; off >>= 1) acc += __shfl_down(acc, off);
        if ((tid & 63) == 0) red[tid >> 6] = acc;
        __syncthreads();
        if (tid == 0) {
            float tot = 0.f;
#pragma unroll
            for (int g = 0; g < 8; ++g) tot += red[g];
            const float np = ninst * (ninst - 1.f) * 0.5f;
            aux[16 + b] = tot / fmaxf(np, 1.f);      // dist_b
            arrive(&bar[512]);                       // auxdone
        }
        __syncthreads();
    }

    // ======== pull pass (emb re-read, L3-hot; smu in LDS) ========
    {
        const float4* epb  = (const float4*)(emb + pw * DD);
        const int*    idsb = ids + pw;
        const int*    mskb = mask + pw;
        float accv = 0.f;
        for (int t = 0; t < NSTG; ++t) {
            const int idr = idsb[t * 64 + lane];
            const int mkr = mskb[t * 64 + lane];
            const int vid = (mkr != 0 && (unsigned)idr < KK) ? idr : -1;
            float4 x[8];
#pragma unroll
            for (int g = 0; g < 8; ++g) x[g] = epb[t * 512 + g * 64 + lane];
#pragma unroll
            for (int g = 0; g < 8; ++g) {
                const int sid = __shfl(vid, g * 8 + pl);
                const int row = (sid >= 0) ? sid : 0;
                const float4 m4 = *(const float4*)&smu[row][4 * pc];
                float a = x[g].x - m4.x; float dsq = a * a;
                a = x[g].y - m4.y; dsq = fmaf(a, a, dsq);
                a = x[g].z - m4.z; dsq = fmaf(a, a, dsq);
                a = x[g].w - m4.w; dsq = fmaf(a, a, dsq);
                dsq += __shfl_xor(dsq, 1);
                dsq += __shfl_xor(dsq, 2);
                dsq += __shfl_xor(dsq, 4);
                if (pc == 0 && sid >= 0) {
                    const float dist = (dsq > 0.f) ? sqrtf(dsq) : 0.f;
                    float pen = fmaxf(dist - DELTA_V, 0.f);
                    accv = fmaf(pen * pen, smu[row][33], accv);
                }
            }
        }
        for (int off = 32; off; off >>= 1) accv += __shfl_down(accv, off);
        if (lane == 0) red[w] = accv;
        __syncthreads();
        if (tid == 0) {
            float s = 0.f;
#pragma unroll
            for (int g = 0; g < 8; ++g) s += red[g];
            varpart[gblk] = s;
        }
    }

    // ======== done-ticket: last-arriving block combines ========
    if (tid == 0) {
        const int ret = __hip_atomic_fetch_add(&bar[544], 1, __ATOMIC_RELEASE,
                                               __HIP_MEMORY_SCOPE_AGENT);
        s_last = (ret == GRID - 1) ? 1 : 0;
        if (s_last) spinge(&bar[512], BB);   // auxdone
    }
    __syncthreads();
    if (s_last) {
        if (tid < BB) {
            float vs = 0.f;
            for (int j = 0; j < 32; ++j) vs += varpart[tid * 32 + j];
            const float ni = aux[32 + tid];
            sf[0][tid] = vs / fmaxf(ni, 1.f);
            sf[1][tid] = (ni >= 2.f) ? 1.f : 0.f;
            sf[2][tid] = aux[tid];
            sf[3][tid] = aux[16 + tid];
        }
        __syncthreads();
        if (tid == 0) {
            float denom = 0.f, v = 0.f, d = 0.f, r = 0.f;
            for (int bb = 0; bb < BB; ++bb) {
                const float vb = sf[1][bb];
                denom += vb;
                v += sf[0][bb] * vb;
                d += sf[3][bb] * vb;
                r += sf[2][bb] * vb;
            }
            denom = fmaxf(denom, 1.f);
            v /= denom; d /= denom; r /= denom;
            out[0] = v + d + 0.001f * r;   // ALPHA=BETA=1, GAMMA=0.001
            out[1] = v;
            out[2] = d;
            out[3] = r;
        }
    }
}

// ---------------------------------------------------------------------------
extern "C" void kernel_launch(void* const* d_in, const int* in_sizes, int n_in,
                              void* d_out, int out_size, void* d_ws, size_t ws_size,
                              hipStream_t stream)
{
    const float* emb  = (const float*)d_in[0];
    const int*   ids  = (const int*)d_in[1];
    const int*   mask = (const int*)d_in[2];   // bool widened to int32

    float* ws      = (float*)d_ws;
    int*   bar     = (int*)ws;                              // 2048 ints
    float* parts   = ws + 2048;                             // 512*2048
    float* pcnt    = parts + (size_t)GRID * 2048;           // 512*64
    float* mu      = pcnt + (size_t)GRID * KK;              // 16*64*36
    float* varpart = mu + (size_t)BB * KK * 36;             // 512
    float* aux     = varpart + GRID;                        // 48

    k_init<<<1, 64, 0, stream>>>(bar);
    k_fused<<<GRID, 512, 0, stream>>>(emb, ids, mask, parts, pcnt, mu,
                                      varpart, aux, bar, (float*)d_out);
}

// Round 11
// 92.407 us; speedup vs baseline: 1.1089x; 1.1089x over previous
//
#include <hip/hip_runtime.h>
#include <cstdint>

#define BB 16
#define NN 65536
#define DD 32
#define KK 64
#define DELTA_V 0.5f
#define DELTA_D 1.5f

typedef short bf16x8 __attribute__((ext_vector_type(8)));
typedef float f32x16 __attribute__((ext_vector_type(16)));

__device__ __forceinline__ short f2bf(float x) {
    union { float f; unsigned u; } v; v.f = x;
    const unsigned r = v.u + 0x7FFFu + ((v.u >> 16) & 1u);  // RNE
    return (short)(r >> 16);
}

// ---------------------------------------------------------------------------
// Kernel 1: one-hot MFMA segment-sum, NO LDS in the hot loop.
// B-fragment loaded directly from global in fragment layout:
//   lane l, elem e  ->  emb[pt0 + (l>>5)*8 + e][l&31]
// (for fixed e: two contiguous 128B runs per wave = fully coalesced).
// LDS used only once at block end for the 4-wave reduce.
// ---------------------------------------------------------------------------
#define K1_BPB 64                    // blocks per batch -> grid 1024
#define K1_PPB 1024                  // points per block (4 waves x 256)

__global__ __launch_bounds__(256, 4) void k_accum(
    const float* __restrict__ emb, const int* __restrict__ ids,
    const int* __restrict__ mask, float* __restrict__ parts,
    float* __restrict__ pcnt)
{
    __shared__ float tbl[4][64][32];  // 32 KB, used only at the end
    __shared__ float lc2[4][64];
    const int tid  = threadIdx.x;
    const int w    = tid >> 6, lane = tid & 63;
    const int half = lane >> 5, d32 = lane & 31;
    const int b    = blockIdx.x >> 6;
    const int blk  = blockIdx.x & 63;
    const size_t pw = (size_t)b * NN + (size_t)blk * K1_PPB + (size_t)w * 256;

    f32x16 acc0 = {}, acc1 = {};
    int c0 = 0, c1 = 0;
    const int m0 = d32, m1 = d32 + 32;

    const int* idsb = ids + pw;
    const int* mskb = mask + pw;
    // fragment-layout base: point pw + half*8, dim d32
    const float* eb = emb + (pw + (size_t)half * 8) * DD + d32;

    float xa[32], xb[32];
    int idr, mkr;
#pragma unroll
    for (int j = 0; j < 32; ++j)
        xa[j] = eb[(size_t)(((j >> 3) * 16) + (j & 7)) * DD];
    idr = idsb[lane]; mkr = mskb[lane];

#pragma unroll
    for (int s = 0; s < 4; ++s) {                 // 4 stages of 64 points
        int idr2 = 0, mkr2 = 0;
        if (s < 3) {                              // prefetch next stage
            const float* eb2 = eb + (size_t)(s + 1) * 64 * DD;
#pragma unroll
            for (int j = 0; j < 32; ++j)
                xb[j] = eb2[(size_t)(((j >> 3) * 16) + (j & 7)) * DD];
            idr2 = idsb[(s + 1) * 64 + lane];
            mkr2 = mskb[(s + 1) * 64 + lane];
        }
        const int vid = (mkr != 0 && (unsigned)idr < KK) ? idr : -1;
#pragma unroll
        for (int q = 0; q < 4; ++q) {             // 16-point MFMA pairs
            bf16x8 bfB, a0, a1;
#pragma unroll
            for (int e = 0; e < 8; ++e) {
                bfB[e] = f2bf(xa[q * 8 + e]);
                const int s_lo = __builtin_amdgcn_readlane(vid, q * 16 + e);
                const int s_hi = __builtin_amdgcn_readlane(vid, q * 16 + 8 + e);
                const int sel  = half ? s_hi : s_lo;
                const bool h0 = (sel == m0), h1 = (sel == m1);
                a0[e] = h0 ? (short)0x3F80 : (short)0;   // bf16 1.0
                a1[e] = h1 ? (short)0x3F80 : (short)0;
                c0 += h0 ? 1 : 0;
                c1 += h1 ? 1 : 0;
            }
            acc0 = __builtin_amdgcn_mfma_f32_32x32x16_bf16(a0, bfB, acc0, 0, 0, 0);
            acc1 = __builtin_amdgcn_mfma_f32_32x32x16_bf16(a1, bfB, acc1, 0, 0, 0);
        }
        if (s < 3) {
#pragma unroll
            for (int j = 0; j < 32; ++j) xa[j] = xb[j];
            idr = idr2; mkr = mkr2;
        }
    }

    // park C fragments (verified C/D layout) and 4-wave block reduce
#pragma unroll
    for (int r = 0; r < 16; ++r) {
        const int mrow = (r & 3) + 8 * (r >> 2) + 4 * half;
        tbl[w][mrow][d32]      = acc0[r];
        tbl[w][32 + mrow][d32] = acc1[r];
    }
    c0 += __shfl_down(c0, 32);
    c1 += __shfl_down(c1, 32);
    if (lane < 32) { lc2[w][lane] = (float)c0; lc2[w][lane + 32] = (float)c1; }
    __syncthreads();

    float* pb = parts + (size_t)blockIdx.x * 2048;
    for (int i = tid; i < 2048; i += 256) {
        const int row = i >> 5, col = i & 31;
        pb[i] = tbl[0][row][col] + tbl[1][row][col]
              + tbl[2][row][col] + tbl[3][row][col];
    }
    if (tid < KK)
        pcnt[(size_t)blockIdx.x * KK + tid] =
            lc2[0][tid] + lc2[1][tid] + lc2[2][tid] + lc2[3][tid];
}

// ---------------------------------------------------------------------------
// Kernel 2: fold 64 partials/batch -> mu[b][k][36] (d:0-31, 32=count,
// 33=1/max(count,1)), then per-batch reg loss + pairwise push loss.
// ---------------------------------------------------------------------------
__global__ __launch_bounds__(256) void k_reduce_push(
    const float* __restrict__ parts, const float* __restrict__ pcnt,
    float* __restrict__ mu, float* __restrict__ regb,
    float* __restrict__ distb)
{
    const int b = blockIdx.x;
    const int tid = threadIdx.x;
    __shared__ float lm[KK][DD + 1];
    __shared__ float lcnt[KK];
    __shared__ float red[4];

    if (tid < KK) {
        float s = 0.f;
        for (int j = 0; j < K1_BPB; ++j)
            s += pcnt[((size_t)b * K1_BPB + j) * KK + tid];
        lcnt[tid] = s;
        mu[(size_t)b * KK * 36 + tid * 36 + 32] = s;
        mu[(size_t)b * KK * 36 + tid * 36 + 33] = 1.f / fmaxf(s, 1.f);
    }
    __syncthreads();

    for (int e = tid; e < KK * DD; e += 256) {
        float s = 0.f;
        for (int j = 0; j < K1_BPB; ++j)
            s += parts[((size_t)b * K1_BPB + j) * (KK * DD) + e];
        const int k = e >> 5, d = e & 31;
        const float m = s / fmaxf(lcnt[k], 1.f);
        lm[k][d] = m;
        mu[(size_t)b * KK * 36 + k * 36 + d] = m;
    }
    __syncthreads();

    float ninst = 0.f;
    if (tid < KK) {
        const float c = lcnt[tid];
        const float pres = (c > 0.f) ? 1.f : 0.f;
        float sq = 0.f;
#pragma unroll
        for (int d = 0; d < DD; ++d) { const float m = lm[tid][d]; sq = fmaf(m, m, sq); }
        float nm = ((sq > 0.f) ? sqrtf(sq) : 0.f) * pres;
        float pn = pres;
        for (int off = 32; off; off >>= 1) {
            pn += __shfl_down(pn, off);
            nm += __shfl_down(nm, off);
        }
        if (tid == 0) {
            ninst = pn;
            regb[b] = nm / fmaxf(pn, 1.f);
        }
    }

    float acc = 0.f;
    for (int idx = tid; idx < KK * KK; idx += 256) {
        const int i = idx >> 6, j = idx & 63;
        if (i < j && lcnt[i] > 0.f && lcnt[j] > 0.f) {
            float dsq = 0.f;
#pragma unroll
            for (int d = 0; d < DD; ++d) {
                const float df = lm[i][d] - lm[j][d];
                dsq = fmaf(df, df, dsq);
            }
            const float pd = (dsq > 0.f) ? sqrtf(dsq) : 0.f;
            const float pen = fmaxf(2.f * DELTA_D - pd, 0.f);
            acc = fmaf(pen, pen, acc);
        }
    }
    for (int off = 32; off; off >>= 1) acc += __shfl_down(acc, off);
    if ((tid & 63) == 0) red[tid >> 6] = acc;
    __syncthreads();
    if (tid == 0) {
        const float tot = red[0] + red[1] + red[2] + red[3];
        const float np = ninst * (ninst - 1.f) * 0.5f;
        distb[b] = tot / fmaxf(np, 1.f);
    }
}

// ---------------------------------------------------------------------------
// Kernel 3: pull (variance) pass, fully coalesced (R7-proven).
// ---------------------------------------------------------------------------
#define K2_BPB 64
#define K2_PTS 1024

__global__ __launch_bounds__(256) void k_pull(
    const float* __restrict__ emb, const int* __restrict__ ids,
    const int* __restrict__ mask, const float* __restrict__ mu,
    float* __restrict__ varpart)
{
    __shared__ float smu[KK][36];
    __shared__ float red[4];
    const int tid = threadIdx.x;
    const int w = tid >> 6, lane = tid & 63;
    const int pl = lane >> 3;
    const int pc = lane & 7;
    const int b   = blockIdx.x >> 6;
    const int blk = blockIdx.x & 63;

    const float* mub = mu + (size_t)b * KK * 36;
    for (int i = tid; i < KK * 36; i += 256) ((float*)smu)[i] = mub[i];
    __syncthreads();

    const size_t p0 = (size_t)b * NN + (size_t)blk * K2_PTS + (size_t)w * 256;
    float accv = 0.f;
    for (int t = 0; t < 4; ++t) {
        const size_t pt0 = p0 + t * 64;
        const int idr = ids[pt0 + lane];
        const int mkr = mask[pt0 + lane];
        const int vid = (mkr != 0 && (unsigned)idr < KK) ? idr : -1;
        const float4* ep4 = (const float4*)(emb + pt0 * DD);
#pragma unroll
        for (int g = 0; g < 8; ++g) {
            const float4 x = ep4[g * 64 + lane];
            const int sid = __shfl(vid, g * 8 + pl);
            const int row = (sid >= 0) ? sid : 0;
            const float4 m4 = *(const float4*)&smu[row][4 * pc];
            float a = x.x - m4.x; float dsq = a * a;
            a = x.y - m4.y; dsq = fmaf(a, a, dsq);
            a = x.z - m4.z; dsq = fmaf(a, a, dsq);
            a = x.w - m4.w; dsq = fmaf(a, a, dsq);
            dsq += __shfl_xor(dsq, 1);
            dsq += __shfl_xor(dsq, 2);
            dsq += __shfl_xor(dsq, 4);
            if (pc == 0 && sid >= 0) {
                const float dist = (dsq > 0.f) ? sqrtf(dsq) : 0.f;
                float pen = fmaxf(dist - DELTA_V, 0.f);
                accv = fmaf(pen * pen, smu[row][33], accv);
            }
        }
    }
    for (int off = 32; off; off >>= 1) accv += __shfl_down(accv, off);
    if (lane == 0) red[w] = accv;
    __syncthreads();
    if (tid == 0)
        varpart[blockIdx.x] = red[0] + red[1] + red[2] + red[3];
}

// ---------------------------------------------------------------------------
// Kernel 4: final combine -> 4 outputs
// ---------------------------------------------------------------------------
__global__ __launch_bounds__(64) void k_final(
    const float* __restrict__ mu, const float* __restrict__ varpart,
    const float* __restrict__ regb, const float* __restrict__ distb,
    float* __restrict__ out)
{
    const int tid = threadIdx.x;
    __shared__ float s_var[BB], s_valid[BB];
    if (tid < BB) {
        const int b = tid;
        float ni = 0.f;
        for (int k = 0; k < KK; ++k)
            ni += (mu[(size_t)b * KK * 36 + k * 36 + 32] > 0.f) ? 1.f : 0.f;
        float vs = 0.f;
        for (int j = 0; j < K2_BPB; ++j) vs += varpart[b * K2_BPB + j];
        s_var[tid]   = vs / fmaxf(ni, 1.f);
        s_valid[tid] = (ni >= 2.f) ? 1.f : 0.f;
    }
    __syncthreads();
    if (tid == 0) {
        float denom = 0.f, v = 0.f, d = 0.f, r = 0.f;
        for (int b = 0; b < BB; ++b) {
            const float vb = s_valid[b];
            denom += vb;
            v += s_var[b] * vb;
            d += distb[b] * vb;
            r += regb[b] * vb;
        }
        denom = fmaxf(denom, 1.f);
        v /= denom; d /= denom; r /= denom;
        out[0] = v + d + 0.001f * r;   // ALPHA=BETA=1, GAMMA=0.001
        out[1] = v;
        out[2] = d;
        out[3] = r;
    }
}

// ---------------------------------------------------------------------------
extern "C" void kernel_launch(void* const* d_in, const int* in_sizes, int n_in,
                              void* d_out, int out_size, void* d_ws, size_t ws_size,
                              hipStream_t stream)
{
    const float* emb  = (const float*)d_in[0];
    const int*   ids  = (const int*)d_in[1];
    const int*   mask = (const int*)d_in[2];   // bool widened to int32

    float* ws      = (float*)d_ws;
    float* parts   = ws;                                        // 1024*2048
    float* pcnt    = parts + (size_t)BB * K1_BPB * KK * DD;     // 1024*64
    float* mu      = pcnt + (size_t)BB * K1_BPB * KK;           // 16*64*36
    float* varpart = mu + (size_t)BB * KK * 36;                 // 1024
    float* regb    = varpart + BB * K2_BPB;                     // 16
    float* distb   = regb + BB;                                 // 16

    k_accum<<<BB * K1_BPB, 256, 0, stream>>>(emb, ids, mask, parts, pcnt);
    k_reduce_push<<<BB, 256, 0, stream>>>(parts, pcnt, mu, regb, distb);
    k_pull<<<BB * K2_BPB, 256, 0, stream>>>(emb, ids, mask, mu, varpart);
    k_final<<<1, 64, 0, stream>>>(mu, varpart, regb, distb, (float*)d_out);
}